// Round 1
// baseline (888.135 us; speedup 1.0000x reference)
//
#include <hip/hip_runtime.h>

// ---------------------------------------------------------------------------
// RowLSTM on MI355X.
// Phases:
//   prep_kernel : pack bf16 MFMA A-fragments of w_cell (gate-interleaved row
//                 permutation) and of the 1x3 row convs (im2col over K=120).
//   conv7_kernel: the two 7x7 convs (full + mask-A) -> is_ws[b][t][m][w]
//                 with m = permuted combined-channel index (bias folded in).
//   rnn_kernel  : 16 blocks (1 per batch item) x 640 threads (10 waves).
//                 Row loop: 1x3 convs via MFMA over hst/cst (bf16 state in
//                 LDS), then 7 layers of (160x40 GEMM via mfma_16x16x32_bf16
//                 + lane-local LSTM gates). Channel permutation makes each
//                 lane's 4 acc regs = (i,f,o,g) of one cell channel.
//   out_kernel  : 1x1 conv 40->256 + ReLU, fp32 register-tiled.
// ---------------------------------------------------------------------------

typedef __bf16 bf16x8 __attribute__((ext_vector_type(8)));
typedef __bf16 bf16x4 __attribute__((ext_vector_type(4)));
typedef float  f32x4  __attribute__((ext_vector_type(4)));

__device__ __forceinline__ float fast_sigmoid(float x) {
    float t = __builtin_amdgcn_exp2f(-1.44269504f * x);
    return __builtin_amdgcn_rcpf(1.0f + t);
}
__device__ __forceinline__ float fast_tanh(float x) {
    float t = __builtin_amdgcn_exp2f(-2.88539008f * x);
    return 2.0f * __builtin_amdgcn_rcpf(1.0f + t) - 1.0f;
}

// physical (permuted) combined-row p -> original combined row (gate*40 + cc)
// p = mt*16 + q4*4 + r  ->  cc = 4*mt + q4, gate = r
__device__ __forceinline__ int orig_row(int p) {
    return (p & 3) * 40 + ((p >> 4) << 2) + ((p >> 2) & 3);
}

// ---------------------------------------------------------------------------
__global__ __launch_bounds__(256) void prep_kernel(
        const float* __restrict__ wcell, const float* __restrict__ wrh,
        const float* __restrict__ wrc, __bf16* __restrict__ wsA_cell,
        __bf16* __restrict__ wsA_conv) {
    int i = blockIdx.x * blockDim.x + threadIdx.x;
    const int total_cell = 7 * 10 * 2 * 64 * 8;   // [l][mt][ks][lane][j]
    if (i < total_cell) {
        int j = i & 7;
        int lane = (i >> 3) & 63;
        int ks = (i >> 9) & 1;
        int lm = i >> 10;           // l*10 + mt
        int mt = lm % 10, l = lm / 10;
        int k = ks * 32 + (lane >> 4) * 8 + j;  // A[m][k], k = quad*8+j
        int p = mt * 16 + (lane & 15);          // m = lane&15
        float v = (k < 40) ? wcell[(l * 160 + orig_row(p)) * 40 + k] : 0.0f;
        wsA_cell[i] = (__bf16)v;
    } else {
        int i2 = i - total_cell;
        const int total_conv = 2 * 3 * 4 * 64 * 8;  // [cv][mt][ks][lane][j]
        if (i2 < total_conv) {
            int j = i2 & 7;
            int lane = (i2 >> 3) & 63;
            int ks = (i2 >> 9) & 3;
            int cm = i2 >> 11;       // cv*3 + mt
            int mt = cm % 3, cv = cm / 3;
            int ch = mt * 16 + (lane & 15);
            int k = ks * 32 + (lane >> 4) * 8 + j;  // k = kin*3 + d (im2col)
            const float* w = cv ? wrc : wrh;        // [40][40*3] row-major
            float v = (ch < 40 && k < 120) ? w[ch * 120 + k] : 0.0f;
            wsA_conv[i2] = (__bf16)v;
        }
    }
}

// ---------------------------------------------------------------------------
// 7x7 convs. block = 256 (w=0..63, q=0..3). q<2: full conv of input (orig ch
// 0..79), q>=2: mask-A conv of target (orig ch 80..159). Output at permuted
// channel index, bias folded in. is_ws layout [b][t][m][w].
__global__ __launch_bounds__(256) void conv7_kernel(
        const float* __restrict__ inp, const float* __restrict__ tgt,
        const float* __restrict__ w_is, const float* __restrict__ b_is,
        const float* __restrict__ w_cis, const float* __restrict__ b_cis,
        float* __restrict__ is_ws) {
    int b = blockIdx.x >> 6, y = blockIdx.x & 63;
    int w = threadIdx.x & 63, q = threadIdx.x >> 6;
    const float* sb = ((q < 2) ? inp : tgt) + b * 4096;
    float patch[7][7];
#pragma unroll
    for (int dy = 0; dy < 7; dy++) {
        int yy = y + dy - 3;
#pragma unroll
        for (int dx = 0; dx < 7; dx++) {
            int xx = w + dx - 3;
            patch[dy][dx] = (yy >= 0 && yy < 64 && xx >= 0 && xx < 64)
                                ? sb[yy * 64 + xx] : 0.0f;
        }
    }
    float* outb = is_ws + (size_t)(b * 64 + y) * 160 * 64;
    if (q < 2) {
        for (int mm = 0; mm < 40; mm++) {
            int o = q * 40 + mm;                  // orig combined ch 0..79
            float acc = b_cis[o];
            const float* wp = w_cis + o * 49;
#pragma unroll
            for (int dy = 0; dy < 7; dy++)
#pragma unroll
                for (int dx = 0; dx < 7; dx++)
                    acc += wp[dy * 7 + dx] * patch[dy][dx];
            int gate = o / 40, cc = o % 40;
            int p = (cc >> 2) * 16 + (cc & 3) * 4 + gate;
            outb[p * 64 + w] = acc;
        }
    } else {
        for (int mm = 0; mm < 40; mm++) {
            int oc = (q - 2) * 40 + mm;           // 0..79
            int o = 80 + oc;                      // orig combined ch 80..159
            float acc = b_is[oc];
            const float* wp = w_is + oc * 49;
            // mask A: rows 0..2 full, row 3 cols 0..2, center excluded
#pragma unroll
            for (int dy = 0; dy < 3; dy++)
#pragma unroll
                for (int dx = 0; dx < 7; dx++)
                    acc += wp[dy * 7 + dx] * patch[dy][dx];
#pragma unroll
            for (int dx = 0; dx < 3; dx++)
                acc += wp[3 * 7 + dx] * patch[3][dx];
            int gate = o / 40, cc = o % 40;
            int p = (cc >> 2) * 16 + (cc & 3) * 4 + gate;
            outb[p * 64 + w] = acc;
        }
    }
}

// ---------------------------------------------------------------------------
__global__ __launch_bounds__(640, 1) void rnn_kernel(
        const float* __restrict__ is_ws, const __bf16* __restrict__ wsA_cell,
        const __bf16* __restrict__ wsA_conv, const float* __restrict__ b_rh,
        const float* __restrict__ b_rc, const float* __restrict__ b_cell,
        float* __restrict__ hid_ws) {
    // hst/cst: bf16 state with halo col (w stored at col w+1), rows 40..43
    // zero-padded for im2col K up to 128 (kin<=42).
    __shared__ __bf16 hst[44 * 66];
    __shared__ __bf16 cst[44 * 66];
    // double-buffered transposed h [w][ch], ch-stride 72 (cols 40..71 zero)
    __shared__ __bf16 hbuf[2][64 * 72];
    __shared__ float  cb[40 * 66];
    __shared__ float  bc_l[7 * 160];
    __shared__ float  brh_l[40];
    __shared__ float  brc_l[40];

    const int b = blockIdx.x;
    const int tid = threadIdx.x;
    const int wv = tid >> 6, lane = tid & 63;
    const int q = lane >> 4, l16 = lane & 15;
    const int cc = wv * 4 + q;    // this lane's cell channel (0..39)

    for (int i = tid; i < 44 * 66; i += 640) {
        hst[i] = (__bf16)0.0f;
        cst[i] = (__bf16)0.0f;
    }
    {
        __bf16* hz = &hbuf[0][0];
        for (int i = tid; i < 2 * 64 * 72; i += 640) hz[i] = (__bf16)0.0f;
    }
    for (int i = tid; i < 7 * 160; i += 640) bc_l[i] = b_cell[i];
    if (tid < 40) { brh_l[tid] = b_rh[tid]; brc_l[tid] = b_rc[tid]; }
    __syncthreads();

    float c_reg[4];

    for (int t = 0; t < 64; t++) {
        // ---- phase A: x preload (regs) + 1x3 convs via MFMA ----
        float xv[4][4];   // [gate r][nt]
        {
            const float* xb =
                is_ws + (size_t)((b * 64 + t) * 160 + wv * 16 + q * 4) * 64;
#pragma unroll
            for (int r = 0; r < 4; r++)
#pragma unroll
                for (int nt = 0; nt < 4; nt++)
                    xv[r][nt] = xb[r * 64 + nt * 16 + l16];
        }
        if (wv < 8) {
            const int cv = wv >> 2, nt = wv & 3;
            const int n = nt * 16 + l16;
            const __bf16* st = cv ? cst : hst;
            f32x4 acc3[3] = {{0.f, 0.f, 0.f, 0.f},
                             {0.f, 0.f, 0.f, 0.f},
                             {0.f, 0.f, 0.f, 0.f}};
            const bf16x8* afp = (const bf16x8*)wsA_conv;
#pragma unroll
            for (int ks = 0; ks < 4; ks++) {
                bf16x8 bfr;
#pragma unroll
                for (int jj = 0; jj < 8; jj++) {
                    int k = ks * 32 + q * 8 + jj;
                    int kin = k / 3;
                    int d = k - kin * 3;
                    // B[k][n] = h[kin][n + d - 1]  (halo offset +1)
                    bfr[jj] = st[kin * 66 + n + d];
                }
#pragma unroll
                for (int mt = 0; mt < 3; mt++) {
                    bf16x8 af = afp[((cv * 3 + mt) * 4 + ks) * 64 + lane];
                    acc3[mt] = __builtin_amdgcn_mfma_f32_16x16x32_bf16(
                        af, bfr, acc3[mt], 0, 0, 0);
                }
            }
#pragma unroll
            for (int mt = 0; mt < 3; mt++) {
                int ch0 = mt * 16 + q * 4;
                if (ch0 < 40) {
                    if (cv == 0) {
                        bf16x4 hv;
#pragma unroll
                        for (int r = 0; r < 4; r++)
                            hv[r] = (__bf16)(acc3[mt][r] + brh_l[ch0 + r]);
                        *(bf16x4*)&hbuf[0][n * 72 + ch0] = hv;
                    } else {
#pragma unroll
                        for (int r = 0; r < 4; r++)
                            cb[(ch0 + r) * 66 + n] = acc3[mt][r] + brc_l[ch0 + r];
                    }
                }
            }
        }
        __syncthreads();

        // ---- phase B: 7 layers ----
        for (int l = 0; l < 7; l++) {
            const __bf16* hb = hbuf[l & 1];
            f32x4 acc[4] = {{0.f, 0.f, 0.f, 0.f},
                            {0.f, 0.f, 0.f, 0.f},
                            {0.f, 0.f, 0.f, 0.f},
                            {0.f, 0.f, 0.f, 0.f}};
            const bf16x8* acp = (const bf16x8*)wsA_cell;
#pragma unroll
            for (int ks = 0; ks < 2; ks++) {
                bf16x8 af = acp[((l * 10 + wv) * 2 + ks) * 64 + lane];
#pragma unroll
                for (int nt = 0; nt < 4; nt++) {
                    bf16x8 bfr = *(const bf16x8*)
                        &hb[(nt * 16 + l16) * 72 + ks * 32 + q * 8];
                    acc[nt] = __builtin_amdgcn_mfma_f32_16x16x32_bf16(
                        af, bfr, acc[nt], 0, 0, 0);
                }
            }
            float bv[4];
#pragma unroll
            for (int r = 0; r < 4; r++) bv[r] = bc_l[l * 160 + r * 40 + cc];
            __bf16* hbn = hbuf[(l + 1) & 1];
#pragma unroll
            for (int nt = 0; nt < 4; nt++) {
                int w = nt * 16 + l16;
                if (l == 0) c_reg[nt] = cb[cc * 66 + w];
                float vi = acc[nt][0] + xv[0][nt] + bv[0];
                float vf = acc[nt][1] + xv[1][nt] + bv[1];
                float vo = acc[nt][2] + xv[2][nt] + bv[2];
                float vg = acc[nt][3] + xv[3][nt] + bv[3];
                float ii = fast_sigmoid(vi);
                float ff = fast_sigmoid(vf);
                float oo = fast_sigmoid(vo);
                float gg = fast_tanh(vg);
                float c = ff * c_reg[nt] + ii * gg;
                c_reg[nt] = c;
                float h = oo * fast_tanh(c);
                if (l < 6) {
                    hbn[w * 72 + cc] = (__bf16)h;
                } else {
                    hst[cc * 66 + 1 + w] = (__bf16)h;
                    cst[cc * 66 + 1 + w] = (__bf16)c;
                    hid_ws[(size_t)((b * 64 + t) * 40 + cc) * 64 + w] = h;
                }
            }
            __syncthreads();
        }
    }
}

// ---------------------------------------------------------------------------
// out[b][o][y][w] = relu(sum_k w_out[o][k]*hid[b][y][k][w] + b_out[o])
// block = 256 per (b,y); 8x8 register tile per thread.
__global__ __launch_bounds__(256) void out_kernel(
        const float* __restrict__ hid_ws, const float* __restrict__ w_out,
        const float* __restrict__ b_out, float* __restrict__ out) {
    __shared__ float wlds[40 * 264];   // transposed [k][o]
    __shared__ float hlds[40 * 64];
    int b = blockIdx.x >> 6, y = blockIdx.x & 63;
    int tid = threadIdx.x;
    for (int i = tid; i < 10240; i += 256) {
        int o = i / 40, k = i - o * 40;
        wlds[k * 264 + o] = w_out[i];
    }
    const float* hbp = hid_ws + (size_t)(b * 64 + y) * 40 * 64;
    for (int i = tid; i < 2560; i += 256) hlds[i] = hbp[i];
    __syncthreads();

    int tn = tid & 7, tm = tid >> 3;
    int wbase = tn * 8, obase = tm * 8;
    float acc[8][8];
#pragma unroll
    for (int io = 0; io < 8; io++)
#pragma unroll
        for (int iw = 0; iw < 8; iw++) acc[io][iw] = 0.0f;

    for (int k = 0; k < 40; k++) {
        f32x4 hA = *(const f32x4*)&hlds[k * 64 + wbase];
        f32x4 hB = *(const f32x4*)&hlds[k * 64 + wbase + 4];
        f32x4 wA = *(const f32x4*)&wlds[k * 264 + obase];
        f32x4 wB = *(const f32x4*)&wlds[k * 264 + obase + 4];
#pragma unroll
        for (int io = 0; io < 8; io++) {
            float wo = (io < 4) ? wA[io] : wB[io - 4];
#pragma unroll
            for (int iw = 0; iw < 8; iw++) {
                float hx = (iw < 4) ? hA[iw] : hB[iw - 4];
                acc[io][iw] = __builtin_fmaf(wo, hx, acc[io][iw]);
            }
        }
    }
#pragma unroll
    for (int io = 0; io < 8; io++) {
        int o = obase + io;
        float bo = b_out[o];
        f32x4 s0, s1;
#pragma unroll
        for (int iw = 0; iw < 4; iw++)
            s0[iw] = fmaxf(acc[io][iw] + bo, 0.0f);
#pragma unroll
        for (int iw = 0; iw < 4; iw++)
            s1[iw] = fmaxf(acc[io][iw + 4] + bo, 0.0f);
        float* ob = out + (size_t)((b * 256 + o) * 64 + y) * 64 + wbase;
        *(f32x4*)ob = s0;
        *(f32x4*)(ob + 4) = s1;
    }
}

// ---------------------------------------------------------------------------
extern "C" void kernel_launch(void* const* d_in, const int* in_sizes, int n_in,
                              void* d_out, int out_size, void* d_ws,
                              size_t ws_size, hipStream_t stream) {
    const float* input  = (const float*)d_in[0];
    const float* target = (const float*)d_in[1];
    const float* w_is   = (const float*)d_in[2];
    const float* b_is   = (const float*)d_in[3];
    const float* w_cis  = (const float*)d_in[4];
    const float* b_cis  = (const float*)d_in[5];
    const float* w_rh   = (const float*)d_in[6];
    const float* b_rh   = (const float*)d_in[7];
    const float* w_rc   = (const float*)d_in[8];
    const float* b_rc   = (const float*)d_in[9];
    const float* w_cell = (const float*)d_in[10];
    const float* b_cell = (const float*)d_in[11];
    const float* w_out  = (const float*)d_in[12];
    const float* b_out  = (const float*)d_in[13];
    float* out = (float*)d_out;

    char* ws = (char*)d_ws;
    float*  is_ws    = (float*)ws;                       // 41,943,040 B
    float*  hid_ws   = (float*)(ws + 41943040);          // 10,485,760 B
    __bf16* wsA_cell = (__bf16*)(ws + 52428800);         //    143,360 B
    __bf16* wsA_conv = (__bf16*)(ws + 52572160);         //     24,576 B

    prep_kernel<<<328, 256, 0, stream>>>(w_cell, w_rh, w_rc, wsA_cell, wsA_conv);
    conv7_kernel<<<1024, 256, 0, stream>>>(input, target, w_is, b_is, w_cis,
                                           b_cis, is_ws);
    rnn_kernel<<<16, 640, 0, stream>>>(is_ws, wsA_cell, wsA_conv, b_rh, b_rc,
                                       b_cell, hid_ws);
    out_kernel<<<1024, 256, 0, stream>>>(hid_ws, w_out, b_out, out);
}